// Round 1
// baseline (11663.685 us; speedup 1.0000x reference)
//
#include <hip/hip_runtime.h>

// ---------------------------------------------------------------------------
// GraphTransformer: x@Wi+bi, then 2x [GAT-ish attention (global softmax over
// all edges per head) + residual + FFN + residual]. All f32.
// ---------------------------------------------------------------------------

// ---------------- GEMM: Y = op(A[M,K] @ W[K,N] + bias) (+R) ----------------
// BM=64, BN=128, BK=32. block=256 (16x16), per-thread 4 rows x 8 cols.
template<bool RELU, bool RES>
__global__ __launch_bounds__(256)
void gemm_k(const float* __restrict__ A, const float* __restrict__ W,
            const float* __restrict__ bias, const float* __restrict__ R,
            float* __restrict__ Y, int M, int K, int N) {
  __shared__ float Xs[32][64];    // transposed: Xs[k][row]
  __shared__ float Ws[32][128];   // Ws[k][col]
  const int t  = threadIdx.x;
  const int tx = t & 15, ty = t >> 4;
  const int row0 = blockIdx.x * 64;
  const int col0 = blockIdx.y * 128;

  float acc[4][8];
#pragma unroll
  for (int i = 0; i < 4; i++)
#pragma unroll
    for (int j = 0; j < 8; j++) acc[i][j] = 0.f;

  const int lrow = t >> 2;         // 0..63 (X tile row)
  const int lk   = (t & 3) * 8;    // k offset within tile
  const int wrow = t >> 3;         // 0..31 (W tile row = k)
  const int wcol = (t & 7) * 16;   // 0..112
  const int grow = (row0 + lrow < M) ? (row0 + lrow) : (M - 1);

  for (int k0 = 0; k0 < K; k0 += 32) {
    const float* ap = A + (size_t)grow * K + (k0 + lk);
    float4 x0 = *(const float4*)ap;
    float4 x1 = *(const float4*)(ap + 4);
    Xs[lk + 0][lrow] = x0.x; Xs[lk + 1][lrow] = x0.y;
    Xs[lk + 2][lrow] = x0.z; Xs[lk + 3][lrow] = x0.w;
    Xs[lk + 4][lrow] = x1.x; Xs[lk + 5][lrow] = x1.y;
    Xs[lk + 6][lrow] = x1.z; Xs[lk + 7][lrow] = x1.w;

    const float* wp = W + (size_t)(k0 + wrow) * N + (col0 + wcol);
    float4 w0 = ((const float4*)wp)[0];
    float4 w1 = ((const float4*)wp)[1];
    float4 w2 = ((const float4*)wp)[2];
    float4 w3 = ((const float4*)wp)[3];
    *(float4*)&Ws[wrow][wcol + 0]  = w0;
    *(float4*)&Ws[wrow][wcol + 4]  = w1;
    *(float4*)&Ws[wrow][wcol + 8]  = w2;
    *(float4*)&Ws[wrow][wcol + 12] = w3;
    __syncthreads();

#pragma unroll
    for (int kk = 0; kk < 32; kk++) {
      const float4 a  = *(const float4*)&Xs[kk][ty * 4];
      const float4 b0 = *(const float4*)&Ws[kk][tx * 4];
      const float4 b1 = *(const float4*)&Ws[kk][64 + tx * 4];
      float af[4] = {a.x, a.y, a.z, a.w};
      float bf[8] = {b0.x, b0.y, b0.z, b0.w, b1.x, b1.y, b1.z, b1.w};
#pragma unroll
      for (int i = 0; i < 4; i++)
#pragma unroll
        for (int j = 0; j < 8; j++)
          acc[i][j] = fmaf(af[i], bf[j], acc[i][j]);
    }
    __syncthreads();
  }

  float bb[8];
  {
    float4 b0 = *(const float4*)(bias + col0 + tx * 4);
    float4 b1 = *(const float4*)(bias + col0 + 64 + tx * 4);
    bb[0] = b0.x; bb[1] = b0.y; bb[2] = b0.z; bb[3] = b0.w;
    bb[4] = b1.x; bb[5] = b1.y; bb[6] = b1.z; bb[7] = b1.w;
  }
#pragma unroll
  for (int i = 0; i < 4; i++) {
    int r = row0 + ty * 4 + i;
    if (r < M) {
      float o[8];
#pragma unroll
      for (int j = 0; j < 8; j++) o[j] = acc[i][j] + bb[j];
      if (RES) {
        const float* rp = R + (size_t)r * N + col0;
        float4 r0 = *(const float4*)(rp + tx * 4);
        float4 r1 = *(const float4*)(rp + 64 + tx * 4);
        o[0] += r0.x; o[1] += r0.y; o[2] += r0.z; o[3] += r0.w;
        o[4] += r1.x; o[5] += r1.y; o[6] += r1.z; o[7] += r1.w;
      }
      if (RELU) {
#pragma unroll
        for (int j = 0; j < 8; j++) o[j] = fmaxf(o[j], 0.f);
      }
      float* yp = Y + (size_t)r * N + col0;
      *(float4*)(yp + tx * 4)      = make_float4(o[0], o[1], o[2], o[3]);
      *(float4*)(yp + 64 + tx * 4) = make_float4(o[4], o[5], o[6], o[7]);
    }
  }
}

// ---------------- edge scores: S[e*4+h] = scale * dot(q[dst[e],h], k[src[e],h])
__global__ __launch_bounds__(256)
void scores_k(const float* __restrict__ Q, const float* __restrict__ Km,
              const int* __restrict__ src, const int* __restrict__ dst,
              float* __restrict__ S, int E, float scale) {
  int idx = blockIdx.x * 256 + threadIdx.x;
  if (idx >= E * 4) return;
  int e = idx >> 2, h = idx & 3;
  const float4* qp = (const float4*)(Q + (size_t)dst[e] * 128 + h * 32);
  const float4* kp = (const float4*)(Km + (size_t)src[e] * 128 + h * 32);
  float s = 0.f;
#pragma unroll
  for (int j = 0; j < 8; j++) {
    float4 q4 = qp[j], k4 = kp[j];
    s += q4.x * k4.x + q4.y * k4.y + q4.z * k4.z + q4.w * k4.w;
  }
  S[idx] = s * scale;
}

// ---------------- softmax reductions (deterministic two-stage, per head) ----
__global__ __launch_bounds__(256)
void reduce1_max(const float* __restrict__ S, float* __restrict__ pmax, int total) {
  __shared__ float sm[256];
  int t = threadIdx.x;
  int start = blockIdx.x * 256 + t;
  float v = -__builtin_huge_valf();
  for (int i = start; i < total; i += 256 * 256) v = fmaxf(v, S[i]);
  sm[t] = v; __syncthreads();
  for (int s = 128; s >= 4; s >>= 1) {
    if (t < s) sm[t] = fmaxf(sm[t], sm[t + s]);
    __syncthreads();
  }
  if (t < 4) pmax[blockIdx.x * 4 + t] = sm[t];
}

__global__ __launch_bounds__(256)
void reduce2_max(const float* __restrict__ p, float* __restrict__ m) {
  __shared__ float sm[256];
  int t = threadIdx.x;
  float v = p[t];
  v = fmaxf(v, p[t + 256]); v = fmaxf(v, p[t + 512]); v = fmaxf(v, p[t + 768]);
  sm[t] = v; __syncthreads();
  for (int s = 128; s >= 4; s >>= 1) {
    if (t < s) sm[t] = fmaxf(sm[t], sm[t + s]);
    __syncthreads();
  }
  if (t < 4) m[t] = sm[t];
}

// exp in place + per-block partial sums
__global__ __launch_bounds__(256)
void expsum1(float* __restrict__ S, const float* __restrict__ m,
             float* __restrict__ psum, int total) {
  __shared__ float sm[256];
  int t = threadIdx.x;
  int start = blockIdx.x * 256 + t;
  float mh = m[t & 3];   // (blockIdx*256+t)&3 == t&3 since 256%4==0
  float acc = 0.f;
  for (int i = start; i < total; i += 256 * 256) {
    float a = expf(S[i] - mh);
    S[i] = a;
    acc += a;
  }
  sm[t] = acc; __syncthreads();
  for (int s = 128; s >= 4; s >>= 1) {
    if (t < s) sm[t] += sm[t + s];
    __syncthreads();
  }
  if (t < 4) psum[blockIdx.x * 4 + t] = sm[t];
}

__global__ __launch_bounds__(256)
void reduce2_sum(const float* __restrict__ p, float* __restrict__ iz) {
  __shared__ float sm[256];
  int t = threadIdx.x;
  float v = p[t] + p[t + 256] + p[t + 512] + p[t + 768];
  sm[t] = v; __syncthreads();
  for (int s = 128; s >= 4; s >>= 1) {
    if (t < s) sm[t] += sm[t + s];
    __syncthreads();
  }
  if (t < 4) iz[t] = 1.0f / sm[t];
}

// ---------------- zero fill ----------------
__global__ __launch_bounds__(256)
void zero_k(float4* __restrict__ p, int n4) {
  int i = blockIdx.x * 256 + threadIdx.x;
  if (i < n4) p[i] = make_float4(0.f, 0.f, 0.f, 0.f);
}

// ---------------- aggregation: AG[dst] += (A[e,h]*invZ[h]) * v[src] --------
__global__ __launch_bounds__(256)
void agg_k(const float* __restrict__ A, const float* __restrict__ iz,
           const float* __restrict__ V, const int* __restrict__ src,
           const int* __restrict__ dst, float* __restrict__ AG, int E) {
  int idx = blockIdx.x * 256 + threadIdx.x;
  if (idx >= E * 4) return;
  int e = idx >> 2, h = idx & 3;
  float coef = A[idx] * iz[h];
  const float4* vp = (const float4*)(V + (size_t)src[e] * 128 + h * 32);
  float* ap = AG + (size_t)dst[e] * 128 + h * 32;
#pragma unroll
  for (int j = 0; j < 8; j++) {
    float4 v4 = vp[j];
    atomicAdd(ap + 4 * j + 0, coef * v4.x);
    atomicAdd(ap + 4 * j + 1, coef * v4.y);
    atomicAdd(ap + 4 * j + 2, coef * v4.z);
    atomicAdd(ap + 4 * j + 3, coef * v4.w);
  }
}

// ---------------------------------------------------------------------------
extern "C" void kernel_launch(void* const* d_in, const int* in_sizes, int n_in,
                              void* d_out, int out_size, void* d_ws, size_t ws_size,
                              hipStream_t stream) {
  const float* x_in = (const float*)d_in[0];
  const int*   ei   = (const int*)d_in[1];
  const float* Wi = (const float*)d_in[2];
  const float* bi = (const float*)d_in[3];
  const float* Wq = (const float*)d_in[4];  const float* bq = (const float*)d_in[5];
  const float* Wk = (const float*)d_in[6];  const float* bk = (const float*)d_in[7];
  const float* Wv = (const float*)d_in[8];  const float* bv = (const float*)d_in[9];
  const float* Wo = (const float*)d_in[10]; const float* bo = (const float*)d_in[11];
  const float* W1 = (const float*)d_in[12]; const float* b1 = (const float*)d_in[13];
  const float* W2 = (const float*)d_in[14]; const float* b2 = (const float*)d_in[15];

  const int N = in_sizes[0] / 128;   // 50000
  const int E = in_sizes[1] / 2;     // 800000
  const int* src = ei;
  const int* dst = ei + E;

  // workspace layout (aliased): X(25.6M) V(25.6M) S(12.8M) QKH(51.2M) + small
  char* w = (char*)d_ws;
  auto alloc = [&](size_t bytes) -> float* {
    float* p = (float*)w;
    w += (bytes + 255) & ~(size_t)255;
    return p;
  };
  float* X   = alloc((size_t)N * 128 * 4);
  float* Vb  = alloc((size_t)N * 128 * 4);
  float* S   = alloc((size_t)E * 4 * 4);
  float* QKH = alloc((size_t)N * 256 * 4);
  float* Qb  = QKH;
  float* Kb  = QKH + (size_t)N * 128;
  float* Hb  = QKH;              // FFN hidden reuses Q+K region
  float* AG  = Qb;               // aggregation reuses Q region (Q dead by then)
  float* pmax = alloc(1024 * 4);
  float* psum = alloc(1024 * 4);
  float* m4   = alloc(16);
  float* iz   = alloc(16);

  const float scale = 0.17677669529663687f; // 1/sqrt(32)
  dim3 blk(256);
  dim3 g128((N + 63) / 64, 1);
  dim3 g256((N + 63) / 64, 2);
  const int tot = E * 4;
  const int gE = (tot + 255) / 256;
  const int n4 = N * 32;                 // N*128/4
  const int gZ = (n4 + 255) / 256;

  // input projection
  gemm_k<false, false><<<g128, blk, 0, stream>>>(x_in, Wi, bi, nullptr, X, N, 128, 128);

  for (int l = 0; l < 2; l++) {
    const float* Wq_l = Wq + (size_t)l * 128 * 128; const float* bq_l = bq + l * 128;
    const float* Wk_l = Wk + (size_t)l * 128 * 128; const float* bk_l = bk + l * 128;
    const float* Wv_l = Wv + (size_t)l * 128 * 128; const float* bv_l = bv + l * 128;
    const float* Wo_l = Wo + (size_t)l * 128 * 128; const float* bo_l = bo + l * 128;
    const float* W1_l = W1 + (size_t)l * 128 * 256; const float* b1_l = b1 + l * 256;
    const float* W2_l = W2 + (size_t)l * 256 * 128; const float* b2_l = b2 + l * 128;

    gemm_k<false, false><<<g128, blk, 0, stream>>>(X, Wq_l, bq_l, nullptr, Qb, N, 128, 128);
    gemm_k<false, false><<<g128, blk, 0, stream>>>(X, Wk_l, bk_l, nullptr, Kb, N, 128, 128);
    gemm_k<false, false><<<g128, blk, 0, stream>>>(X, Wv_l, bv_l, nullptr, Vb, N, 128, 128);

    scores_k<<<gE, blk, 0, stream>>>(Qb, Kb, src, dst, S, E, scale);
    reduce1_max<<<256, blk, 0, stream>>>(S, pmax, tot);
    reduce2_max<<<1, blk, 0, stream>>>(pmax, m4);
    expsum1<<<256, blk, 0, stream>>>(S, m4, psum, tot);
    reduce2_sum<<<1, blk, 0, stream>>>(psum, iz);

    zero_k<<<gZ, blk, 0, stream>>>((float4*)AG, n4);
    agg_k<<<gE, blk, 0, stream>>>(S, iz, Vb, src, dst, AG, E);

    // x = x + AG@Wo + bo   (in place into X; residual read is elementwise)
    gemm_k<false, true><<<g128, blk, 0, stream>>>(AG, Wo_l, bo_l, X, X, N, 128, 128);
    // h = relu(x@W1 + b1)
    gemm_k<true, false><<<g256, blk, 0, stream>>>(X, W1_l, b1_l, nullptr, Hb, N, 128, 256);
    // x = x + h@W2 + b2  (final layer writes d_out)
    float* outp = (l == 1) ? (float*)d_out : X;
    gemm_k<false, true><<<g128, blk, 0, stream>>>(Hb, W2_l, b2_l, X, outp, N, 256, 128);
  }
}

// Round 2
// 1415.789 us; speedup vs baseline: 8.2383x; 8.2383x over previous
//
#include <hip/hip_runtime.h>

// ---------------------------------------------------------------------------
// GraphTransformer: x@Wi+bi, then 2x [attention (global softmax over all
// edges per head) + residual + FFN + residual]. All f32.
// R2: atomic scatter-add replaced by CSR build (once) + per-node gather.
// ---------------------------------------------------------------------------

// ---------------- GEMM: Y = op(A[M,K] @ W[K,N] + bias) (+R) ----------------
template<bool RELU, bool RES>
__global__ __launch_bounds__(256)
void gemm_k(const float* __restrict__ A, const float* __restrict__ W,
            const float* __restrict__ bias, const float* __restrict__ R,
            float* __restrict__ Y, int M, int K, int N) {
  __shared__ float Xs[32][64];    // transposed: Xs[k][row]
  __shared__ float Ws[32][128];   // Ws[k][col]
  const int t  = threadIdx.x;
  const int tx = t & 15, ty = t >> 4;
  const int row0 = blockIdx.x * 64;
  const int col0 = blockIdx.y * 128;

  float acc[4][8];
#pragma unroll
  for (int i = 0; i < 4; i++)
#pragma unroll
    for (int j = 0; j < 8; j++) acc[i][j] = 0.f;

  const int lrow = t >> 2;         // 0..63 (X tile row)
  const int lk   = (t & 3) * 8;    // k offset within tile
  const int wrow = t >> 3;         // 0..31 (W tile row = k)
  const int wcol = (t & 7) * 16;   // 0..112
  const int grow = (row0 + lrow < M) ? (row0 + lrow) : (M - 1);

  for (int k0 = 0; k0 < K; k0 += 32) {
    const float* ap = A + (size_t)grow * K + (k0 + lk);
    float4 x0 = *(const float4*)ap;
    float4 x1 = *(const float4*)(ap + 4);
    Xs[lk + 0][lrow] = x0.x; Xs[lk + 1][lrow] = x0.y;
    Xs[lk + 2][lrow] = x0.z; Xs[lk + 3][lrow] = x0.w;
    Xs[lk + 4][lrow] = x1.x; Xs[lk + 5][lrow] = x1.y;
    Xs[lk + 6][lrow] = x1.z; Xs[lk + 7][lrow] = x1.w;

    const float* wp = W + (size_t)(k0 + wrow) * N + (col0 + wcol);
    float4 w0 = ((const float4*)wp)[0];
    float4 w1 = ((const float4*)wp)[1];
    float4 w2 = ((const float4*)wp)[2];
    float4 w3 = ((const float4*)wp)[3];
    *(float4*)&Ws[wrow][wcol + 0]  = w0;
    *(float4*)&Ws[wrow][wcol + 4]  = w1;
    *(float4*)&Ws[wrow][wcol + 8]  = w2;
    *(float4*)&Ws[wrow][wcol + 12] = w3;
    __syncthreads();

#pragma unroll
    for (int kk = 0; kk < 32; kk++) {
      const float4 a  = *(const float4*)&Xs[kk][ty * 4];
      const float4 b0 = *(const float4*)&Ws[kk][tx * 4];
      const float4 b1 = *(const float4*)&Ws[kk][64 + tx * 4];
      float af[4] = {a.x, a.y, a.z, a.w};
      float bf[8] = {b0.x, b0.y, b0.z, b0.w, b1.x, b1.y, b1.z, b1.w};
#pragma unroll
      for (int i = 0; i < 4; i++)
#pragma unroll
        for (int j = 0; j < 8; j++)
          acc[i][j] = fmaf(af[i], bf[j], acc[i][j]);
    }
    __syncthreads();
  }

  float bb[8];
  {
    float4 b0 = *(const float4*)(bias + col0 + tx * 4);
    float4 b1 = *(const float4*)(bias + col0 + 64 + tx * 4);
    bb[0] = b0.x; bb[1] = b0.y; bb[2] = b0.z; bb[3] = b0.w;
    bb[4] = b1.x; bb[5] = b1.y; bb[6] = b1.z; bb[7] = b1.w;
  }
#pragma unroll
  for (int i = 0; i < 4; i++) {
    int r = row0 + ty * 4 + i;
    if (r < M) {
      float o[8];
#pragma unroll
      for (int j = 0; j < 8; j++) o[j] = acc[i][j] + bb[j];
      if (RES) {
        const float* rp = R + (size_t)r * N + col0;
        float4 r0 = *(const float4*)(rp + tx * 4);
        float4 r1 = *(const float4*)(rp + 64 + tx * 4);
        o[0] += r0.x; o[1] += r0.y; o[2] += r0.z; o[3] += r0.w;
        o[4] += r1.x; o[5] += r1.y; o[6] += r1.z; o[7] += r1.w;
      }
      if (RELU) {
#pragma unroll
        for (int j = 0; j < 8; j++) o[j] = fmaxf(o[j], 0.f);
      }
      float* yp = Y + (size_t)r * N + col0;
      *(float4*)(yp + tx * 4)      = make_float4(o[0], o[1], o[2], o[3]);
      *(float4*)(yp + 64 + tx * 4) = make_float4(o[4], o[5], o[6], o[7]);
    }
  }
}

// ---------------- edge scores ----------------
__global__ __launch_bounds__(256)
void scores_k(const float* __restrict__ Q, const float* __restrict__ Km,
              const int* __restrict__ src, const int* __restrict__ dst,
              float* __restrict__ S, int E, float scale) {
  int idx = blockIdx.x * 256 + threadIdx.x;
  if (idx >= E * 4) return;
  int e = idx >> 2, h = idx & 3;
  const float4* qp = (const float4*)(Q + (size_t)dst[e] * 128 + h * 32);
  const float4* kp = (const float4*)(Km + (size_t)src[e] * 128 + h * 32);
  float s = 0.f;
#pragma unroll
  for (int j = 0; j < 8; j++) {
    float4 q4 = qp[j], k4 = kp[j];
    s += q4.x * k4.x + q4.y * k4.y + q4.z * k4.z + q4.w * k4.w;
  }
  S[idx] = s * scale;
}

// ---------------- softmax reductions (deterministic two-stage, per head) ----
__global__ __launch_bounds__(256)
void reduce1_max(const float* __restrict__ S, float* __restrict__ pmax, int total) {
  __shared__ float sm[256];
  int t = threadIdx.x;
  int start = blockIdx.x * 256 + t;
  float v = -__builtin_huge_valf();
  for (int i = start; i < total; i += 256 * 256) v = fmaxf(v, S[i]);
  sm[t] = v; __syncthreads();
  for (int s = 128; s >= 4; s >>= 1) {
    if (t < s) sm[t] = fmaxf(sm[t], sm[t + s]);
    __syncthreads();
  }
  if (t < 4) pmax[blockIdx.x * 4 + t] = sm[t];
}

__global__ __launch_bounds__(256)
void reduce2_max(const float* __restrict__ p, float* __restrict__ m) {
  __shared__ float sm[256];
  int t = threadIdx.x;
  float v = p[t];
  v = fmaxf(v, p[t + 256]); v = fmaxf(v, p[t + 512]); v = fmaxf(v, p[t + 768]);
  sm[t] = v; __syncthreads();
  for (int s = 128; s >= 4; s >>= 1) {
    if (t < s) sm[t] = fmaxf(sm[t], sm[t + s]);
    __syncthreads();
  }
  if (t < 4) m[t] = sm[t];
}

__global__ __launch_bounds__(256)
void expsum1(float* __restrict__ S, const float* __restrict__ m,
             float* __restrict__ psum, int total) {
  __shared__ float sm[256];
  int t = threadIdx.x;
  int start = blockIdx.x * 256 + t;
  float mh = m[t & 3];
  float acc = 0.f;
  for (int i = start; i < total; i += 256 * 256) {
    float a = expf(S[i] - mh);
    S[i] = a;
    acc += a;
  }
  sm[t] = acc; __syncthreads();
  for (int s = 128; s >= 4; s >>= 1) {
    if (t < s) sm[t] += sm[t + s];
    __syncthreads();
  }
  if (t < 4) psum[blockIdx.x * 4 + t] = sm[t];
}

__global__ __launch_bounds__(256)
void reduce2_sum(const float* __restrict__ p, float* __restrict__ iz) {
  __shared__ float sm[256];
  int t = threadIdx.x;
  float v = p[t] + p[t + 256] + p[t + 512] + p[t + 768];
  sm[t] = v; __syncthreads();
  for (int s = 128; s >= 4; s >>= 1) {
    if (t < s) sm[t] += sm[t + s];
    __syncthreads();
  }
  if (t < 4) iz[t] = 1.0f / sm[t];
}

// ---------------- CSR build ----------------
__global__ __launch_bounds__(256)
void zeroi_k(int* __restrict__ p, int n) {
  int i = blockIdx.x * 256 + threadIdx.x;
  if (i < n) p[i] = 0;
}

__global__ __launch_bounds__(256)
void hist_k(const int* __restrict__ dst, int* __restrict__ cnt, int E) {
  int i = blockIdx.x * 256 + threadIdx.x;
  if (i < E) atomicAdd(&cnt[dst[i]], 1);
}

// single-block exclusive scan over N counters -> off[0..N]
__global__ __launch_bounds__(256)
void scan_k(const int* __restrict__ cnt, int* __restrict__ off, int N) {
  __shared__ int sm[256];
  int t = threadIdx.x;
  int chunk = (N + 255) / 256;
  int lo = t * chunk, hi = lo + chunk; if (hi > N) hi = N; if (lo > N) lo = N;
  int s = 0;
  for (int i = lo; i < hi; i++) s += cnt[i];
  sm[t] = s; __syncthreads();
  for (int d = 1; d < 256; d <<= 1) {
    int v = (t >= d) ? sm[t - d] : 0;
    __syncthreads();
    sm[t] += v;
    __syncthreads();
  }
  int run = sm[t] - s;   // exclusive prefix for this chunk
  for (int i = lo; i < hi; i++) { off[i] = run; run += cnt[i]; }
  if (t == 255) off[N] = run;
}

__global__ __launch_bounds__(256)
void scatter_k(const int* __restrict__ dst, const int* __restrict__ off,
               int* __restrict__ cur, int* __restrict__ perm, int E) {
  int e = blockIdx.x * 256 + threadIdx.x;
  if (e < E) {
    int d = dst[e];
    int p = atomicAdd(&cur[d], 1);
    perm[off[d] + p] = e;
  }
}

// make bucket order deterministic (sort edge ids ascending per node)
__global__ __launch_bounds__(256)
void sortbuckets_k(const int* __restrict__ off, int* __restrict__ perm, int N) {
  int n = blockIdx.x * 256 + threadIdx.x;
  if (n >= N) return;
  int lo = off[n], hi = off[n + 1];
  for (int i = lo + 1; i < hi; i++) {
    int key = perm[i];
    int j = i - 1;
    while (j >= lo && perm[j] > key) { perm[j + 1] = perm[j]; j--; }
    perm[j + 1] = key;
  }
}

// ---------------- aggregation by gather: AG[n,t] = sum_e coef(e,h)*V[src,t]
__global__ __launch_bounds__(256)
void gatheragg_k(const float* __restrict__ S, const float* __restrict__ iz,
                 const float* __restrict__ V, const int* __restrict__ src,
                 const int* __restrict__ off, const int* __restrict__ perm,
                 float* __restrict__ AG, int N) {
  int node = blockIdx.x * 2 + (threadIdx.x >> 7);
  if (node >= N) return;
  int t = threadIdx.x & 127;       // output element 0..127
  int h = t >> 5;                  // head
  float izh = iz[h];
  int lo = off[node], hi = off[node + 1];
  float acc = 0.f;
  for (int i = lo; i < hi; i++) {
    int e = perm[i];
    float coef = S[e * 4 + h] * izh;
    acc = fmaf(coef, V[(size_t)src[e] * 128 + t], acc);
  }
  AG[(size_t)node * 128 + t] = acc;
}

// ---------------------------------------------------------------------------
extern "C" void kernel_launch(void* const* d_in, const int* in_sizes, int n_in,
                              void* d_out, int out_size, void* d_ws, size_t ws_size,
                              hipStream_t stream) {
  const float* x_in = (const float*)d_in[0];
  const int*   ei   = (const int*)d_in[1];
  const float* Wi = (const float*)d_in[2];
  const float* bi = (const float*)d_in[3];
  const float* Wq = (const float*)d_in[4];  const float* bq = (const float*)d_in[5];
  const float* Wk = (const float*)d_in[6];  const float* bk = (const float*)d_in[7];
  const float* Wv = (const float*)d_in[8];  const float* bv = (const float*)d_in[9];
  const float* Wo = (const float*)d_in[10]; const float* bo = (const float*)d_in[11];
  const float* W1 = (const float*)d_in[12]; const float* b1 = (const float*)d_in[13];
  const float* W2 = (const float*)d_in[14]; const float* b2 = (const float*)d_in[15];

  const int N = in_sizes[0] / 128;   // 50000
  const int E = in_sizes[1] / 2;     // 800000
  const int* src = ei;
  const int* dst = ei + E;

  char* w = (char*)d_ws;
  auto alloc = [&](size_t bytes) -> char* {
    char* p = w;
    w += (bytes + 255) & ~(size_t)255;
    return p;
  };
  float* X   = (float*)alloc((size_t)N * 128 * 4);
  float* Vb  = (float*)alloc((size_t)N * 128 * 4);
  float* S   = (float*)alloc((size_t)E * 4 * 4);
  float* QKH = (float*)alloc((size_t)N * 256 * 4);
  float* Qb  = QKH;
  float* Kb  = QKH + (size_t)N * 128;
  float* Hb  = QKH;              // FFN hidden reuses Q+K region
  float* AG  = Qb;               // aggregation output reuses Q region
  float* pmax = (float*)alloc(1024 * 4);
  float* psum = (float*)alloc(1024 * 4);
  float* m4   = (float*)alloc(16);
  float* iz   = (float*)alloc(16);
  int* cnt  = (int*)alloc((size_t)N * 4);
  int* off  = (int*)alloc((size_t)(N + 1) * 4);
  int* cur  = (int*)alloc((size_t)N * 4);
  int* perm = (int*)alloc((size_t)E * 4);

  const float scale = 0.17677669529663687f; // 1/sqrt(32)
  dim3 blk(256);
  dim3 g128((N + 63) / 64, 1);
  dim3 g256((N + 63) / 64, 2);
  const int tot = E * 4;
  const int gE = (tot + 255) / 256;
  const int gEe = (E + 255) / 256;
  const int gN = (N + 255) / 256;
  const int gAgg = (N + 1) / 2;

  // ---- CSR build (edge_index constant across layers; rebuilt every call) ----
  zeroi_k<<<gN, blk, 0, stream>>>(cnt, N);
  zeroi_k<<<gN, blk, 0, stream>>>(cur, N);
  hist_k<<<gEe, blk, 0, stream>>>(dst, cnt, E);
  scan_k<<<1, blk, 0, stream>>>(cnt, off, N);
  scatter_k<<<gEe, blk, 0, stream>>>(dst, off, cur, perm, E);
  sortbuckets_k<<<gN, blk, 0, stream>>>(off, perm, N);

  // ---- input projection ----
  gemm_k<false, false><<<g128, blk, 0, stream>>>(x_in, Wi, bi, nullptr, X, N, 128, 128);

  for (int l = 0; l < 2; l++) {
    const float* Wq_l = Wq + (size_t)l * 128 * 128; const float* bq_l = bq + l * 128;
    const float* Wk_l = Wk + (size_t)l * 128 * 128; const float* bk_l = bk + l * 128;
    const float* Wv_l = Wv + (size_t)l * 128 * 128; const float* bv_l = bv + l * 128;
    const float* Wo_l = Wo + (size_t)l * 128 * 128; const float* bo_l = bo + l * 128;
    const float* W1_l = W1 + (size_t)l * 128 * 256; const float* b1_l = b1 + l * 256;
    const float* W2_l = W2 + (size_t)l * 256 * 128; const float* b2_l = b2 + l * 128;

    gemm_k<false, false><<<g128, blk, 0, stream>>>(X, Wq_l, bq_l, nullptr, Qb, N, 128, 128);
    gemm_k<false, false><<<g128, blk, 0, stream>>>(X, Wk_l, bk_l, nullptr, Kb, N, 128, 128);
    gemm_k<false, false><<<g128, blk, 0, stream>>>(X, Wv_l, bv_l, nullptr, Vb, N, 128, 128);

    scores_k<<<gE, blk, 0, stream>>>(Qb, Kb, src, dst, S, E, scale);
    reduce1_max<<<256, blk, 0, stream>>>(S, pmax, tot);
    reduce2_max<<<1, blk, 0, stream>>>(pmax, m4);
    expsum1<<<256, blk, 0, stream>>>(S, m4, psum, tot);
    reduce2_sum<<<1, blk, 0, stream>>>(psum, iz);

    gatheragg_k<<<gAgg, blk, 0, stream>>>(S, iz, Vb, src, off, perm, AG, N);

    // x = x + AG@Wo + bo
    gemm_k<false, true><<<g128, blk, 0, stream>>>(AG, Wo_l, bo_l, X, X, N, 128, 128);
    // h = relu(x@W1 + b1)
    gemm_k<true, false><<<g256, blk, 0, stream>>>(X, W1_l, b1_l, nullptr, Hb, N, 128, 256);
    // x = x + h@W2 + b2  (final layer writes d_out)
    float* outp = (l == 1) ? (float*)d_out : X;
    gemm_k<false, true><<<g128, blk, 0, stream>>>(Hb, W2_l, b2_l, X, outp, N, 256, 128);
  }
}

// Round 3
// 1025.250 us; speedup vs baseline: 11.3764x; 1.3809x over previous
//
#include <hip/hip_runtime.h>

// ---------------------------------------------------------------------------
// GraphTransformer. R3: perm-ordered edge metadata (srcP/dstP), scores written
// in perm order, ILP-batched gather aggregation; 128x128 f32 GEMM tile.
// ---------------------------------------------------------------------------

// ---------------- GEMM: Y = op(A[M,K] @ W[K,N] + bias) (+R) ----------------
// BM=128, BN=128, BK=32. block=256 (16x16), per-thread 8x8 (2x2 split @64).
template<bool RELU, bool RES>
__global__ __launch_bounds__(256)
void gemm_k(const float* __restrict__ A, const float* __restrict__ W,
            const float* __restrict__ bias, const float* __restrict__ R,
            float* __restrict__ Y, int M, int K, int N) {
  __shared__ float Xs[32][132];   // transposed: Xs[k][row], pad for banks/align
  __shared__ float Ws[32][128];   // Ws[k][col]
  const int t  = threadIdx.x;
  const int tx = t & 15, ty = t >> 4;
  const int row0 = blockIdx.x * 128;
  const int col0 = blockIdx.y * 128;

  float acc[8][8];
#pragma unroll
  for (int i = 0; i < 8; i++)
#pragma unroll
    for (int j = 0; j < 8; j++) acc[i][j] = 0.f;

  const int arow = t >> 2;         // 0..63
  const int ak   = (t & 3) * 8;    // 0,8,16,24
  const int wrow = t >> 3;         // 0..31
  const int wcol = (t & 7) * 4;    // 0..28, chunks at +0,+32,+64,+96

  for (int k0 = 0; k0 < K; k0 += 32) {
#pragma unroll
    for (int p = 0; p < 2; p++) {
      int r = row0 + arow + p * 64;
      int gr = (r < M) ? r : (M - 1);
      const float* ap = A + (size_t)gr * K + k0 + ak;
      float4 x0 = *(const float4*)ap;
      float4 x1 = *(const float4*)(ap + 4);
      int rr = arow + p * 64;
      Xs[ak + 0][rr] = x0.x; Xs[ak + 1][rr] = x0.y;
      Xs[ak + 2][rr] = x0.z; Xs[ak + 3][rr] = x0.w;
      Xs[ak + 4][rr] = x1.x; Xs[ak + 5][rr] = x1.y;
      Xs[ak + 6][rr] = x1.z; Xs[ak + 7][rr] = x1.w;
    }
    const float* wp = W + (size_t)(k0 + wrow) * N + col0 + wcol;
#pragma unroll
    for (int q = 0; q < 4; q++) {
      float4 wv = *(const float4*)(wp + q * 32);
      *(float4*)&Ws[wrow][wcol + q * 32] = wv;
    }
    __syncthreads();

#pragma unroll
    for (int kk = 0; kk < 32; kk++) {
      const float4 a0 = *(const float4*)&Xs[kk][ty * 4];
      const float4 a1 = *(const float4*)&Xs[kk][64 + ty * 4];
      const float4 b0 = *(const float4*)&Ws[kk][tx * 4];
      const float4 b1 = *(const float4*)&Ws[kk][64 + tx * 4];
      float af[8] = {a0.x, a0.y, a0.z, a0.w, a1.x, a1.y, a1.z, a1.w};
      float bf[8] = {b0.x, b0.y, b0.z, b0.w, b1.x, b1.y, b1.z, b1.w};
#pragma unroll
      for (int i = 0; i < 8; i++)
#pragma unroll
        for (int j = 0; j < 8; j++)
          acc[i][j] = fmaf(af[i], bf[j], acc[i][j]);
    }
    __syncthreads();
  }

  float bb[8];
  {
    float4 b0 = *(const float4*)(bias + col0 + tx * 4);
    float4 b1 = *(const float4*)(bias + col0 + 64 + tx * 4);
    bb[0] = b0.x; bb[1] = b0.y; bb[2] = b0.z; bb[3] = b0.w;
    bb[4] = b1.x; bb[5] = b1.y; bb[6] = b1.z; bb[7] = b1.w;
  }
#pragma unroll
  for (int i = 0; i < 8; i++) {
    int r = row0 + (i >> 2) * 64 + ty * 4 + (i & 3);
    if (r < M) {
      float o[8];
#pragma unroll
      for (int j = 0; j < 8; j++) o[j] = acc[i][j] + bb[j];
      if (RES) {
        const float* rp = R + (size_t)r * N + col0;
        float4 r0 = *(const float4*)(rp + tx * 4);
        float4 r1 = *(const float4*)(rp + 64 + tx * 4);
        o[0] += r0.x; o[1] += r0.y; o[2] += r0.z; o[3] += r0.w;
        o[4] += r1.x; o[5] += r1.y; o[6] += r1.z; o[7] += r1.w;
      }
      if (RELU) {
#pragma unroll
        for (int j = 0; j < 8; j++) o[j] = fmaxf(o[j], 0.f);
      }
      float* yp = Y + (size_t)r * N + col0;
      *(float4*)(yp + tx * 4)      = make_float4(o[0], o[1], o[2], o[3]);
      *(float4*)(yp + 64 + tx * 4) = make_float4(o[4], o[5], o[6], o[7]);
    }
  }
}

// ---------------- edge scores in perm order ----------------
// Sp[i*4+h] = scale * dot(q[dstP[i],h], k[srcP[i],h]); dstP sorted -> locality
__global__ __launch_bounds__(256)
void scores_k(const float* __restrict__ Q, const float* __restrict__ Km,
              const int* __restrict__ srcP, const int* __restrict__ dstP,
              float* __restrict__ Sp, int E, float scale) {
  int idx = blockIdx.x * 256 + threadIdx.x;
  if (idx >= E * 4) return;
  int i = idx >> 2, h = idx & 3;
  const float4* qp = (const float4*)(Q + (size_t)dstP[i] * 128 + h * 32);
  const float4* kp = (const float4*)(Km + (size_t)srcP[i] * 128 + h * 32);
  float s = 0.f;
#pragma unroll
  for (int j = 0; j < 8; j++) {
    float4 q4 = qp[j], k4 = kp[j];
    s += q4.x * k4.x + q4.y * k4.y + q4.z * k4.z + q4.w * k4.w;
  }
  Sp[idx] = s * scale;
}

// ---------------- softmax reductions (deterministic two-stage, per head) ----
__global__ __launch_bounds__(256)
void reduce1_max(const float* __restrict__ S, float* __restrict__ pmax, int total) {
  __shared__ float sm[256];
  int t = threadIdx.x;
  int start = blockIdx.x * 256 + t;
  float v = -__builtin_huge_valf();
  for (int i = start; i < total; i += 256 * 256) v = fmaxf(v, S[i]);
  sm[t] = v; __syncthreads();
  for (int s = 128; s >= 4; s >>= 1) {
    if (t < s) sm[t] = fmaxf(sm[t], sm[t + s]);
    __syncthreads();
  }
  if (t < 4) pmax[blockIdx.x * 4 + t] = sm[t];
}

__global__ __launch_bounds__(256)
void reduce2_max(const float* __restrict__ p, float* __restrict__ m) {
  __shared__ float sm[256];
  int t = threadIdx.x;
  float v = p[t];
  v = fmaxf(v, p[t + 256]); v = fmaxf(v, p[t + 512]); v = fmaxf(v, p[t + 768]);
  sm[t] = v; __syncthreads();
  for (int s = 128; s >= 4; s >>= 1) {
    if (t < s) sm[t] = fmaxf(sm[t], sm[t + s]);
    __syncthreads();
  }
  if (t < 4) m[t] = sm[t];
}

__global__ __launch_bounds__(256)
void expsum1(float* __restrict__ S, const float* __restrict__ m,
             float* __restrict__ psum, int total) {
  __shared__ float sm[256];
  int t = threadIdx.x;
  int start = blockIdx.x * 256 + t;
  float mh = m[t & 3];
  float acc = 0.f;
  for (int i = start; i < total; i += 256 * 256) {
    float a = expf(S[i] - mh);
    S[i] = a;
    acc += a;
  }
  sm[t] = acc; __syncthreads();
  for (int s = 128; s >= 4; s >>= 1) {
    if (t < s) sm[t] += sm[t + s];
    __syncthreads();
  }
  if (t < 4) psum[blockIdx.x * 4 + t] = sm[t];
}

__global__ __launch_bounds__(256)
void reduce2_sum(const float* __restrict__ p, float* __restrict__ iz) {
  __shared__ float sm[256];
  int t = threadIdx.x;
  float v = p[t] + p[t + 256] + p[t + 512] + p[t + 768];
  sm[t] = v; __syncthreads();
  for (int s = 128; s >= 4; s >>= 1) {
    if (t < s) sm[t] += sm[t + s];
    __syncthreads();
  }
  if (t < 4) iz[t] = 1.0f / sm[t];
}

// ---------------- CSR build ----------------
__global__ __launch_bounds__(256)
void zeroi_k(int* __restrict__ p, int n) {
  int i = blockIdx.x * 256 + threadIdx.x;
  if (i < n) p[i] = 0;
}

__global__ __launch_bounds__(256)
void hist_k(const int* __restrict__ dst, int* __restrict__ cnt, int E) {
  int i = blockIdx.x * 256 + threadIdx.x;
  if (i < E) atomicAdd(&cnt[dst[i]], 1);
}

__global__ __launch_bounds__(256)
void scan_k(const int* __restrict__ cnt, int* __restrict__ off, int N) {
  __shared__ int sm[256];
  int t = threadIdx.x;
  int chunk = (N + 255) / 256;
  int lo = t * chunk, hi = lo + chunk; if (hi > N) hi = N; if (lo > N) lo = N;
  int s = 0;
  for (int i = lo; i < hi; i++) s += cnt[i];
  sm[t] = s; __syncthreads();
  for (int d = 1; d < 256; d <<= 1) {
    int v = (t >= d) ? sm[t - d] : 0;
    __syncthreads();
    sm[t] += v;
    __syncthreads();
  }
  int run = sm[t] - s;
  for (int i = lo; i < hi; i++) { off[i] = run; run += cnt[i]; }
  if (t == 255) off[N] = run;
}

__global__ __launch_bounds__(256)
void scatter_k(const int* __restrict__ dst, const int* __restrict__ off,
               int* __restrict__ cur, int* __restrict__ perm, int E) {
  int e = blockIdx.x * 256 + threadIdx.x;
  if (e < E) {
    int d = dst[e];
    int p = atomicAdd(&cur[d], 1);
    perm[off[d] + p] = e;
  }
}

__global__ __launch_bounds__(256)
void sortbuckets_k(const int* __restrict__ off, int* __restrict__ perm, int N) {
  int n = blockIdx.x * 256 + threadIdx.x;
  if (n >= N) return;
  int lo = off[n], hi = off[n + 1];
  for (int i = lo + 1; i < hi; i++) {
    int key = perm[i];
    int j = i - 1;
    while (j >= lo && perm[j] > key) { perm[j + 1] = perm[j]; j--; }
    perm[j + 1] = key;
  }
}

// srcP/dstP in perm order (removes indirection from hot loops)
__global__ __launch_bounds__(256)
void meta_k(const int* __restrict__ perm, const int* __restrict__ src,
            const int* __restrict__ dst, int* __restrict__ srcP,
            int* __restrict__ dstP, int E) {
  int i = blockIdx.x * 256 + threadIdx.x;
  if (i < E) {
    int e = perm[i];
    srcP[i] = src[e];
    dstP[i] = dst[e];
  }
}

// ---------------- aggregation: wave per node, float2 per lane, batched x4 ---
__global__ __launch_bounds__(256)
void gatheragg_k(const float* __restrict__ Sp, const float* __restrict__ iz,
                 const float* __restrict__ V, const int* __restrict__ srcP,
                 const int* __restrict__ off, float* __restrict__ AG, int N) {
  int node = blockIdx.x * 4 + (threadIdx.x >> 6);
  if (node >= N) return;
  int l = threadIdx.x & 63;        // lane: owns cols {2l, 2l+1}
  int h = l >> 4;                  // head
  float izh = iz[h];
  int lo = off[node], hi = off[node + 1];
  const float2* V2 = (const float2*)V;
  float ax = 0.f, ay = 0.f;
  int i = lo;
  for (; i + 4 <= hi; i += 4) {
    int s0 = srcP[i], s1 = srcP[i + 1], s2 = srcP[i + 2], s3 = srcP[i + 3];
    float c0 = Sp[i * 4 + h];
    float c1 = Sp[(i + 1) * 4 + h];
    float c2 = Sp[(i + 2) * 4 + h];
    float c3 = Sp[(i + 3) * 4 + h];
    float2 v0 = V2[(size_t)s0 * 64 + l];
    float2 v1 = V2[(size_t)s1 * 64 + l];
    float2 v2 = V2[(size_t)s2 * 64 + l];
    float2 v3 = V2[(size_t)s3 * 64 + l];
    c0 *= izh; c1 *= izh; c2 *= izh; c3 *= izh;
    ax = fmaf(c0, v0.x, ax); ay = fmaf(c0, v0.y, ay);
    ax = fmaf(c1, v1.x, ax); ay = fmaf(c1, v1.y, ay);
    ax = fmaf(c2, v2.x, ax); ay = fmaf(c2, v2.y, ay);
    ax = fmaf(c3, v3.x, ax); ay = fmaf(c3, v3.y, ay);
  }
  for (; i < hi; i++) {
    int s = srcP[i];
    float c = Sp[i * 4 + h] * izh;
    float2 v = V2[(size_t)s * 64 + l];
    ax = fmaf(c, v.x, ax); ay = fmaf(c, v.y, ay);
  }
  ((float2*)AG)[(size_t)node * 64 + l] = make_float2(ax, ay);
}

// ---------------------------------------------------------------------------
extern "C" void kernel_launch(void* const* d_in, const int* in_sizes, int n_in,
                              void* d_out, int out_size, void* d_ws, size_t ws_size,
                              hipStream_t stream) {
  const float* x_in = (const float*)d_in[0];
  const int*   ei   = (const int*)d_in[1];
  const float* Wi = (const float*)d_in[2];
  const float* bi = (const float*)d_in[3];
  const float* Wq = (const float*)d_in[4];  const float* bq = (const float*)d_in[5];
  const float* Wk = (const float*)d_in[6];  const float* bk = (const float*)d_in[7];
  const float* Wv = (const float*)d_in[8];  const float* bv = (const float*)d_in[9];
  const float* Wo = (const float*)d_in[10]; const float* bo = (const float*)d_in[11];
  const float* W1 = (const float*)d_in[12]; const float* b1 = (const float*)d_in[13];
  const float* W2 = (const float*)d_in[14]; const float* b2 = (const float*)d_in[15];

  const int N = in_sizes[0] / 128;   // 50000
  const int E = in_sizes[1] / 2;     // 800000
  const int* src = ei;
  const int* dst = ei + E;

  char* w = (char*)d_ws;
  auto alloc = [&](size_t bytes) -> char* {
    char* p = w;
    w += (bytes + 255) & ~(size_t)255;
    return p;
  };
  float* X   = (float*)alloc((size_t)N * 128 * 4);
  float* Vb  = (float*)alloc((size_t)N * 128 * 4);
  float* Sp  = (float*)alloc((size_t)E * 4 * 4);
  float* QKH = (float*)alloc((size_t)N * 256 * 4);
  float* Qb  = QKH;
  float* Kb  = QKH + (size_t)N * 128;
  float* Hb  = QKH;              // FFN hidden reuses Q+K region
  float* AG  = Qb;               // aggregation output reuses Q region
  float* pmax = (float*)alloc(1024 * 4);
  float* psum = (float*)alloc(1024 * 4);
  float* m4   = (float*)alloc(16);
  float* iz   = (float*)alloc(16);
  int* cnt  = (int*)alloc((size_t)N * 4);
  int* off  = (int*)alloc((size_t)(N + 1) * 4);
  int* cur  = (int*)alloc((size_t)N * 4);
  int* perm = (int*)alloc((size_t)E * 4);
  int* srcP = (int*)alloc((size_t)E * 4);
  int* dstP = (int*)alloc((size_t)E * 4);

  const float scale = 0.17677669529663687f; // 1/sqrt(32)
  dim3 blk(256);
  dim3 g128((N + 127) / 128, 1);
  dim3 g256((N + 127) / 128, 2);
  const int tot = E * 4;
  const int gE = (tot + 255) / 256;
  const int gEe = (E + 255) / 256;
  const int gN = (N + 255) / 256;
  const int gAgg = (N + 3) / 4;

  // ---- CSR build ----
  zeroi_k<<<gN, blk, 0, stream>>>(cnt, N);
  zeroi_k<<<gN, blk, 0, stream>>>(cur, N);
  hist_k<<<gEe, blk, 0, stream>>>(dst, cnt, E);
  scan_k<<<1, blk, 0, stream>>>(cnt, off, N);
  scatter_k<<<gEe, blk, 0, stream>>>(dst, off, cur, perm, E);
  sortbuckets_k<<<gN, blk, 0, stream>>>(off, perm, N);
  meta_k<<<gEe, blk, 0, stream>>>(perm, src, dst, srcP, dstP, E);

  // ---- input projection ----
  gemm_k<false, false><<<g128, blk, 0, stream>>>(x_in, Wi, bi, nullptr, X, N, 128, 128);

  for (int l = 0; l < 2; l++) {
    const float* Wq_l = Wq + (size_t)l * 128 * 128; const float* bq_l = bq + l * 128;
    const float* Wk_l = Wk + (size_t)l * 128 * 128; const float* bk_l = bk + l * 128;
    const float* Wv_l = Wv + (size_t)l * 128 * 128; const float* bv_l = bv + l * 128;
    const float* Wo_l = Wo + (size_t)l * 128 * 128; const float* bo_l = bo + l * 128;
    const float* W1_l = W1 + (size_t)l * 128 * 256; const float* b1_l = b1 + l * 256;
    const float* W2_l = W2 + (size_t)l * 256 * 128; const float* b2_l = b2 + l * 128;

    gemm_k<false, false><<<g128, blk, 0, stream>>>(X, Wq_l, bq_l, nullptr, Qb, N, 128, 128);
    gemm_k<false, false><<<g128, blk, 0, stream>>>(X, Wk_l, bk_l, nullptr, Kb, N, 128, 128);
    gemm_k<false, false><<<g128, blk, 0, stream>>>(X, Wv_l, bv_l, nullptr, Vb, N, 128, 128);

    scores_k<<<gE, blk, 0, stream>>>(Qb, Kb, srcP, dstP, Sp, E, scale);
    reduce1_max<<<256, blk, 0, stream>>>(Sp, pmax, tot);
    reduce2_max<<<1, blk, 0, stream>>>(pmax, m4);
    expsum1<<<256, blk, 0, stream>>>(Sp, m4, psum, tot);
    reduce2_sum<<<1, blk, 0, stream>>>(psum, iz);

    gatheragg_k<<<gAgg, blk, 0, stream>>>(Sp, iz, Vb, srcP, off, AG, N);

    // x = x + AG@Wo + bo
    gemm_k<false, true><<<g128, blk, 0, stream>>>(AG, Wo_l, bo_l, X, X, N, 128, 128);
    // h = relu(x@W1 + b1)
    gemm_k<true, false><<<g256, blk, 0, stream>>>(X, W1_l, b1_l, nullptr, Hb, N, 128, 256);
    // x = x + h@W2 + b2  (final layer writes d_out)
    float* outp = (l == 1) ? (float*)d_out : X;
    gemm_k<false, true><<<g128, blk, 0, stream>>>(Hb, W2_l, b2_l, X, outp, N, 256, 128);
  }
}

// Round 4
// 693.027 us; speedup vs baseline: 16.8301x; 1.4794x over previous
//
#include <hip/hip_runtime.h>

// ---------------------------------------------------------------------------
// GraphTransformer R4: all GEMMs via bf16 MFMA (16x16x32), bf16 activations
// for edge kernels, f32 residual stream. CSR gather aggregation.
// ---------------------------------------------------------------------------

typedef __attribute__((ext_vector_type(8))) short bf16x8;
typedef __attribute__((ext_vector_type(4))) float f32x4;

__device__ __forceinline__ unsigned short f2bf_rne(float f) {
  unsigned int u = __builtin_bit_cast(unsigned int, f);
  u = (u + 0x7fffu + ((u >> 16) & 1u)) >> 16;
  return (unsigned short)u;
}
__device__ __forceinline__ float bflo(unsigned int w) {
  return __builtin_bit_cast(float, w << 16);
}
__device__ __forceinline__ float bfhi(unsigned int w) {
  return __builtin_bit_cast(float, w & 0xffff0000u);
}

// ---------------- MFMA GEMM: Y = op(A[M,K]b16 @ W + bias) (+R) -------------
// Bt is W transposed: Bt[n][k] bf16. BM=BN=128, BK=128 chunks. 4 waves 2x2.
template<bool RELU, bool RES, bool OUTF, bool OUTB>
__global__ __launch_bounds__(256, 2)
void mgemm_k(const unsigned short* __restrict__ A,
             const unsigned short* __restrict__ Bt,
             const float* __restrict__ bias, const float* __restrict__ R,
             float* __restrict__ Yf, unsigned short* __restrict__ Yb,
             int M, int K, int N) {
  __shared__ __align__(16) char smem[65536];   // A tile 32KB | B tile 32KB
  const int t = threadIdx.x;
  const int l = t & 63;
  const int w = t >> 6, wm = w >> 1, wn = w & 1;
  const int row0 = blockIdx.x * 128;
  const int col0 = blockIdx.y * 128;

  f32x4 acc[4][4];
#pragma unroll
  for (int m = 0; m < 4; m++)
#pragma unroll
    for (int n = 0; n < 4; n++)
#pragma unroll
      for (int r = 0; r < 4; r++) acc[m][n][r] = 0.f;

  for (int kc = 0; kc < K; kc += 128) {
    if (kc) __syncthreads();
    // stage A tile: 128 rows x 128 bf16 (256B/row), swizzled
#pragma unroll
    for (int j = 0; j < 8; j++) {
      int id = j * 256 + t;
      int row = id >> 4, c16 = id & 15;
      int gr = row0 + row; if (gr >= M) gr = M - 1;
      uint4 val = *(const uint4*)(A + (size_t)gr * K + kc + c16 * 8);
      *(uint4*)(smem + row * 256 + ((c16 * 16) ^ ((row & 7) << 4))) = val;
    }
    // stage B tile (Bt rows = output cols)
#pragma unroll
    for (int j = 0; j < 8; j++) {
      int id = j * 256 + t;
      int row = id >> 4, c16 = id & 15;
      uint4 val = *(const uint4*)(Bt + (size_t)(col0 + row) * K + kc + c16 * 8);
      *(uint4*)(smem + 32768 + row * 256 + ((c16 * 16) ^ ((row & 7) << 4))) = val;
    }
    __syncthreads();

#pragma unroll
    for (int ks = 0; ks < 4; ks++) {
      const int bofs = ks * 64 + (l >> 4) * 16;
      bf16x8 a[4], b[4];
#pragma unroll
      for (int m = 0; m < 4; m++) {
        int r = wm * 64 + m * 16 + (l & 15);
        a[m] = *(const bf16x8*)(smem + r * 256 + (bofs ^ ((r & 7) << 4)));
      }
#pragma unroll
      for (int n = 0; n < 4; n++) {
        int r = wn * 64 + n * 16 + (l & 15);
        b[n] = *(const bf16x8*)(smem + 32768 + r * 256 + (bofs ^ ((r & 7) << 4)));
      }
#pragma unroll
      for (int m = 0; m < 4; m++)
#pragma unroll
        for (int n = 0; n < 4; n++)
          acc[m][n] = __builtin_amdgcn_mfma_f32_16x16x32_bf16(a[m], b[n], acc[m][n], 0, 0, 0);
    }
  }

  // epilogue: C[row][col], row=(l>>4)*4+reg (M), col=l&15 (N)
  const int rbase = row0 + wm * 64 + ((l >> 4) << 2);
  const int cl = l & 15;
#pragma unroll
  for (int n = 0; n < 4; n++) {
    int col = col0 + wn * 64 + n * 16 + cl;
    float bb = bias[col];
#pragma unroll
    for (int m = 0; m < 4; m++) {
      int rtile = rbase + m * 16;
#pragma unroll
      for (int r = 0; r < 4; r++) {
        int row = rtile + r;
        if (row < M) {
          float o = acc[m][n][r] + bb;
          if (RES) o += R[(size_t)row * N + col];
          if (RELU) o = fmaxf(o, 0.f);
          if (OUTF) Yf[(size_t)row * N + col] = o;
          if (OUTB) Yb[(size_t)row * N + col] = f2bf_rne(o);
        }
      }
    }
  }
}

// ---------------- weight transpose+cast: dst[m][n][k] = src[m][k][n] -------
__global__ __launch_bounds__(256)
void wtc_k(const float* __restrict__ src, unsigned short* __restrict__ dst,
           int K, int N, int cnt, int dstStrideM) {
  int o = blockIdx.x * 256 + threadIdx.x;
  int total = cnt * K * N;
  if (o >= total) return;
  int m = o / (K * N);
  int rem = o - m * K * N;
  int n = rem / K;
  int k = rem - n * K;
  dst[(size_t)m * dstStrideM + (size_t)n * K + k] = f2bf_rne(src[(size_t)m * K * N + (size_t)k * N + n]);
}

// bias concat: bqkv[l][384] = bq[l] | bk[l] | bv[l]
__global__ __launch_bounds__(256)
void bcat_k(const float* __restrict__ bq, const float* __restrict__ bk,
            const float* __restrict__ bv, float* __restrict__ bqkv) {
  int idx = blockIdx.x * 256 + threadIdx.x;
  if (idx >= 768) return;
  int l = idx / 384, c = idx - l * 384;
  float v = (c < 128) ? bq[l * 128 + c] : (c < 256) ? bk[l * 128 + c - 128] : bv[l * 128 + c - 256];
  bqkv[idx] = v;
}

// f32 -> bf16 cast, 8 elems/thread
__global__ __launch_bounds__(256)
void xcast_k(const float* __restrict__ x, unsigned short* __restrict__ xb, int n8) {
  int i = blockIdx.x * 256 + threadIdx.x;
  if (i >= n8) return;
  const float4* p = (const float4*)(x + (size_t)i * 8);
  float4 a = p[0], b = p[1];
  ushort4* q = (ushort4*)(xb + (size_t)i * 8);
  q[0] = make_ushort4(f2bf_rne(a.x), f2bf_rne(a.y), f2bf_rne(a.z), f2bf_rne(a.w));
  q[1] = make_ushort4(f2bf_rne(b.x), f2bf_rne(b.y), f2bf_rne(b.z), f2bf_rne(b.w));
}

// ---------------- edge scores (bf16 QKV, [n][384] layout) ------------------
__global__ __launch_bounds__(256)
void scores_k(const unsigned short* __restrict__ QKV,
              const int* __restrict__ srcP, const int* __restrict__ dstP,
              float* __restrict__ Sp, int E, float scale) {
  int idx = blockIdx.x * 256 + threadIdx.x;
  if (idx >= E * 4) return;
  int i = idx >> 2, h = idx & 3;
  const uint4* qp = (const uint4*)(QKV + (size_t)dstP[i] * 384 + h * 32);
  const uint4* kp = (const uint4*)(QKV + (size_t)srcP[i] * 384 + 128 + h * 32);
  float s = 0.f;
#pragma unroll
  for (int j = 0; j < 4; j++) {
    uint4 q4 = qp[j], k4 = kp[j];
    s += bflo(q4.x) * bflo(k4.x) + bfhi(q4.x) * bfhi(k4.x);
    s += bflo(q4.y) * bflo(k4.y) + bfhi(q4.y) * bfhi(k4.y);
    s += bflo(q4.z) * bflo(k4.z) + bfhi(q4.z) * bfhi(k4.z);
    s += bflo(q4.w) * bflo(k4.w) + bfhi(q4.w) * bfhi(k4.w);
  }
  Sp[idx] = s * scale;
}

// ---------------- softmax reductions (two-stage, per head) -----------------
__global__ __launch_bounds__(256)
void reduce1_max(const float* __restrict__ S, float* __restrict__ pmax, int total) {
  __shared__ float sm[256];
  int t = threadIdx.x;
  int start = blockIdx.x * 256 + t;
  float v = -__builtin_huge_valf();
  for (int i = start; i < total; i += 256 * 256) v = fmaxf(v, S[i]);
  sm[t] = v; __syncthreads();
  for (int s = 128; s >= 4; s >>= 1) {
    if (t < s) sm[t] = fmaxf(sm[t], sm[t + s]);
    __syncthreads();
  }
  if (t < 4) pmax[blockIdx.x * 4 + t] = sm[t];
}

__global__ __launch_bounds__(256)
void reduce2_max(const float* __restrict__ p, float* __restrict__ m) {
  __shared__ float sm[256];
  int t = threadIdx.x;
  float v = p[t];
  v = fmaxf(v, p[t + 256]); v = fmaxf(v, p[t + 512]); v = fmaxf(v, p[t + 768]);
  sm[t] = v; __syncthreads();
  for (int s = 128; s >= 4; s >>= 1) {
    if (t < s) sm[t] = fmaxf(sm[t], sm[t + s]);
    __syncthreads();
  }
  if (t < 4) m[t] = sm[t];
}

__global__ __launch_bounds__(256)
void expsum1(float* __restrict__ S, const float* __restrict__ m,
             float* __restrict__ psum, int total) {
  __shared__ float sm[256];
  int t = threadIdx.x;
  int start = blockIdx.x * 256 + t;
  float mh = m[t & 3];
  float acc = 0.f;
  for (int i = start; i < total; i += 256 * 256) {
    float a = expf(S[i] - mh);
    S[i] = a;
    acc += a;
  }
  sm[t] = acc; __syncthreads();
  for (int s = 128; s >= 4; s >>= 1) {
    if (t < s) sm[t] += sm[t + s];
    __syncthreads();
  }
  if (t < 4) psum[blockIdx.x * 4 + t] = sm[t];
}

__global__ __launch_bounds__(256)
void reduce2_sum(const float* __restrict__ p, float* __restrict__ iz) {
  __shared__ float sm[256];
  int t = threadIdx.x;
  float v = p[t] + p[t + 256] + p[t + 512] + p[t + 768];
  sm[t] = v; __syncthreads();
  for (int s = 128; s >= 4; s >>= 1) {
    if (t < s) sm[t] += sm[t + s];
    __syncthreads();
  }
  if (t < 4) iz[t] = 1.0f / sm[t];
}

// ---------------- CSR build ----------------
__global__ __launch_bounds__(256)
void zeroi_k(int* __restrict__ p, int n) {
  int i = blockIdx.x * 256 + threadIdx.x;
  if (i < n) p[i] = 0;
}

__global__ __launch_bounds__(256)
void hist_k(const int* __restrict__ dst, int* __restrict__ cnt, int E) {
  int i = blockIdx.x * 256 + threadIdx.x;
  if (i < E) atomicAdd(&cnt[dst[i]], 1);
}

__global__ __launch_bounds__(256)
void scan_k(const int* __restrict__ cnt, int* __restrict__ off, int N) {
  __shared__ int sm[256];
  int t = threadIdx.x;
  int chunk = (N + 255) / 256;
  int lo = t * chunk, hi = lo + chunk; if (hi > N) hi = N; if (lo > N) lo = N;
  int s = 0;
  for (int i = lo; i < hi; i++) s += cnt[i];
  sm[t] = s; __syncthreads();
  for (int d = 1; d < 256; d <<= 1) {
    int v = (t >= d) ? sm[t - d] : 0;
    __syncthreads();
    sm[t] += v;
    __syncthreads();
  }
  int run = sm[t] - s;
  for (int i = lo; i < hi; i++) { off[i] = run; run += cnt[i]; }
  if (t == 255) off[N] = run;
}

__global__ __launch_bounds__(256)
void scatter_k(const int* __restrict__ dst, const int* __restrict__ off,
               int* __restrict__ cur, int* __restrict__ perm, int E) {
  int e = blockIdx.x * 256 + threadIdx.x;
  if (e < E) {
    int d = dst[e];
    int p = atomicAdd(&cur[d], 1);
    perm[off[d] + p] = e;
  }
}

__global__ __launch_bounds__(256)
void sortbuckets_k(const int* __restrict__ off, int* __restrict__ perm, int N) {
  int n = blockIdx.x * 256 + threadIdx.x;
  if (n >= N) return;
  int lo = off[n], hi = off[n + 1];
  for (int i = lo + 1; i < hi; i++) {
    int key = perm[i];
    int j = i - 1;
    while (j >= lo && perm[j] > key) { perm[j + 1] = perm[j]; j--; }
    perm[j + 1] = key;
  }
}

__global__ __launch_bounds__(256)
void meta_k(const int* __restrict__ perm, const int* __restrict__ src,
            const int* __restrict__ dst, int* __restrict__ srcP,
            int* __restrict__ dstP, int E) {
  int i = blockIdx.x * 256 + threadIdx.x;
  if (i < E) {
    int e = perm[i];
    srcP[i] = src[e];
    dstP[i] = dst[e];
  }
}

// ---------------- aggregation gather (bf16 V inside QKV, bf16 out) ---------
__global__ __launch_bounds__(256)
void gatheragg_k(const float* __restrict__ Sp, const float* __restrict__ iz,
                 const unsigned short* __restrict__ QKV,
                 const int* __restrict__ srcP, const int* __restrict__ off,
                 unsigned short* __restrict__ AGb, int N) {
  int node = blockIdx.x * 4 + (threadIdx.x >> 6);
  if (node >= N) return;
  int l = threadIdx.x & 63;        // lane owns cols {2l, 2l+1}
  int h = l >> 4;
  float izh = iz[h];
  int lo = off[node], hi = off[node + 1];
  float ax = 0.f, ay = 0.f;
  int i = lo;
  for (; i + 4 <= hi; i += 4) {
    int s0 = srcP[i], s1 = srcP[i + 1], s2 = srcP[i + 2], s3 = srcP[i + 3];
    float c0 = Sp[i * 4 + h];
    float c1 = Sp[(i + 1) * 4 + h];
    float c2 = Sp[(i + 2) * 4 + h];
    float c3 = Sp[(i + 3) * 4 + h];
    unsigned int v0 = *(const unsigned int*)(QKV + (size_t)s0 * 384 + 256 + l * 2);
    unsigned int v1 = *(const unsigned int*)(QKV + (size_t)s1 * 384 + 256 + l * 2);
    unsigned int v2 = *(const unsigned int*)(QKV + (size_t)s2 * 384 + 256 + l * 2);
    unsigned int v3 = *(const unsigned int*)(QKV + (size_t)s3 * 384 + 256 + l * 2);
    c0 *= izh; c1 *= izh; c2 *= izh; c3 *= izh;
    ax = fmaf(c0, bflo(v0), ax); ay = fmaf(c0, bfhi(v0), ay);
    ax = fmaf(c1, bflo(v1), ax); ay = fmaf(c1, bfhi(v1), ay);
    ax = fmaf(c2, bflo(v2), ax); ay = fmaf(c2, bfhi(v2), ay);
    ax = fmaf(c3, bflo(v3), ax); ay = fmaf(c3, bfhi(v3), ay);
  }
  for (; i < hi; i++) {
    int s = srcP[i];
    float c = Sp[i * 4 + h] * izh;
    unsigned int v = *(const unsigned int*)(QKV + (size_t)s * 384 + 256 + l * 2);
    ax = fmaf(c, bflo(v), ax); ay = fmaf(c, bfhi(v), ay);
  }
  unsigned int packed = (unsigned int)f2bf_rne(ax) | ((unsigned int)f2bf_rne(ay) << 16);
  ((unsigned int*)AGb)[(size_t)node * 64 + l] = packed;
}

// ---------------------------------------------------------------------------
extern "C" void kernel_launch(void* const* d_in, const int* in_sizes, int n_in,
                              void* d_out, int out_size, void* d_ws, size_t ws_size,
                              hipStream_t stream) {
  const float* x_in = (const float*)d_in[0];
  const int*   ei   = (const int*)d_in[1];
  const float* Wi = (const float*)d_in[2];
  const float* bi = (const float*)d_in[3];
  const float* Wq = (const float*)d_in[4];  const float* bq = (const float*)d_in[5];
  const float* Wk = (const float*)d_in[6];  const float* bk = (const float*)d_in[7];
  const float* Wv = (const float*)d_in[8];  const float* bv = (const float*)d_in[9];
  const float* Wo = (const float*)d_in[10]; const float* bo = (const float*)d_in[11];
  const float* W1 = (const float*)d_in[12]; const float* b1 = (const float*)d_in[13];
  const float* W2 = (const float*)d_in[14]; const float* b2 = (const float*)d_in[15];

  const int N = in_sizes[0] / 128;   // 50000
  const int E = in_sizes[1] / 2;     // 800000
  const int* src = ei;
  const int* dst = ei + E;

  char* w = (char*)d_ws;
  auto alloc = [&](size_t bytes) -> char* {
    char* p = w;
    w += (bytes + 255) & ~(size_t)255;
    return p;
  };
  float*          X    = (float*)alloc((size_t)N * 128 * 4);
  unsigned short* Xb   = (unsigned short*)alloc((size_t)N * 128 * 2);
  unsigned short* QKVb = (unsigned short*)alloc((size_t)N * 384 * 2);
  unsigned short* Hb   = QKVb;                 // FFN hidden aliases QKV (dead)
  unsigned short* AGb  = (unsigned short*)alloc((size_t)N * 128 * 2);
  float*          Sp   = (float*)alloc((size_t)E * 4 * 4);
  float* pmax = (float*)alloc(1024 * 4);
  float* psum = (float*)alloc(1024 * 4);
  float* m4   = (float*)alloc(16);
  float* iz   = (float*)alloc(16);
  unsigned short* WiT   = (unsigned short*)alloc(16384 * 2);
  unsigned short* WqkvT = (unsigned short*)alloc((size_t)2 * 384 * 128 * 2);
  unsigned short* WoT   = (unsigned short*)alloc((size_t)2 * 16384 * 2);
  unsigned short* W1T   = (unsigned short*)alloc((size_t)2 * 32768 * 2);
  unsigned short* W2T   = (unsigned short*)alloc((size_t)2 * 32768 * 2);
  float* bqkv = (float*)alloc(768 * 4);
  int* cnt  = (int*)alloc((size_t)N * 4);
  int* off  = (int*)alloc((size_t)(N + 1) * 4);
  int* cur  = (int*)alloc((size_t)N * 4);
  int* perm = (int*)alloc((size_t)E * 4);
  int* srcP = (int*)alloc((size_t)E * 4);
  int* dstP = (int*)alloc((size_t)E * 4);

  const float scale = 0.17677669529663687f; // 1/sqrt(32)
  dim3 blk(256);
  const int gx = (N + 127) / 128;            // 391
  dim3 g1(gx, 1), g2(gx, 2), g3(gx, 3);
  const int tot = E * 4;
  const int gE = (tot + 255) / 256;
  const int gEe = (E + 255) / 256;
  const int gN = (N + 255) / 256;
  const int gAgg = (N + 3) / 4;

  // ---- CSR build ----
  zeroi_k<<<gN, blk, 0, stream>>>(cnt, N);
  zeroi_k<<<gN, blk, 0, stream>>>(cur, N);
  hist_k<<<gEe, blk, 0, stream>>>(dst, cnt, E);
  scan_k<<<1, blk, 0, stream>>>(cnt, off, N);
  scatter_k<<<gEe, blk, 0, stream>>>(dst, off, cur, perm, E);
  sortbuckets_k<<<gN, blk, 0, stream>>>(off, perm, N);
  meta_k<<<gEe, blk, 0, stream>>>(perm, src, dst, srcP, dstP, E);

  // ---- weight prep (transpose + bf16 cast) ----
  wtc_k<<<(16384 + 255) / 256, blk, 0, stream>>>(Wi, WiT, 128, 128, 1, 16384);
  wtc_k<<<(2 * 16384 + 255) / 256, blk, 0, stream>>>(Wq, WqkvT, 128, 128, 2, 384 * 128);
  wtc_k<<<(2 * 16384 + 255) / 256, blk, 0, stream>>>(Wk, WqkvT + 128 * 128, 128, 128, 2, 384 * 128);
  wtc_k<<<(2 * 16384 + 255) / 256, blk, 0, stream>>>(Wv, WqkvT + 256 * 128, 128, 128, 2, 384 * 128);
  wtc_k<<<(2 * 16384 + 255) / 256, blk, 0, stream>>>(Wo, WoT, 128, 128, 2, 16384);
  wtc_k<<<(2 * 32768 + 255) / 256, blk, 0, stream>>>(W1, W1T, 128, 256, 2, 32768);
  wtc_k<<<(2 * 32768 + 255) / 256, blk, 0, stream>>>(W2, W2T, 256, 128, 2, 32768);
  bcat_k<<<3, blk, 0, stream>>>(bq, bk, bv, bqkv);

  // ---- input cast + projection ----
  xcast_k<<<(N * 16 + 255) / 256, blk, 0, stream>>>(x_in, Xb, N * 16);
  // X = x_in @ Wi + bi  (f32 + bf16 outputs); A input is Xb-cast of x_in? No:
  // use Xb as scratch input first, then overwrite: stage via AGb? Simpler:
  // cast x_in into AGb region (N*128 bf16 fits), then write X/Xb.
  // (AGb unused until aggregation.)
  xcast_k<<<(N * 16 + 255) / 256, blk, 0, stream>>>(x_in, AGb, N * 16);
  mgemm_k<false, false, true, true><<<g1, blk, 0, stream>>>(AGb, WiT, bi, nullptr, X, Xb, N, 128, 128);

  for (int l = 0; l < 2; l++) {
    const float* bo_l = bo + l * 128;
    const float* b1_l = b1 + l * 256;
    const float* b2_l = b2 + l * 128;

    // QKV fused: [N][384] bf16
    mgemm_k<false, false, false, true><<<g3, blk, 0, stream>>>(
        Xb, WqkvT + (size_t)l * 384 * 128, bqkv + l * 384, nullptr, nullptr, QKVb, N, 128, 384);

    scores_k<<<gE, blk, 0, stream>>>(QKVb, srcP, dstP, Sp, E, scale);
    reduce1_max<<<256, blk, 0, stream>>>(Sp, pmax, tot);
    reduce2_max<<<1, blk, 0, stream>>>(pmax, m4);
    expsum1<<<256, blk, 0, stream>>>(Sp, m4, psum, tot);
    reduce2_sum<<<1, blk, 0, stream>>>(psum, iz);

    gatheragg_k<<<gAgg, blk, 0, stream>>>(Sp, iz, QKVb, srcP, off, AGb, N);

    // x = x + AG@Wo + bo
    mgemm_k<false, true, true, true><<<g1, blk, 0, stream>>>(
        AGb, WoT + (size_t)l * 16384, bo_l, X, X, Xb, N, 128, 128);
    // h = relu(x@W1 + b1), bf16 only
    mgemm_k<true, false, false, true><<<g2, blk, 0, stream>>>(
        Xb, W1T + (size_t)l * 32768, b1_l, nullptr, nullptr, Hb, N, 128, 256);
    // x = x + h@W2 + b2
    if (l == 0) {
      mgemm_k<false, true, true, true><<<g1, blk, 0, stream>>>(
          Hb, W2T + (size_t)l * 32768, b2_l, X, X, Xb, N, 256, 128);
    } else {
      mgemm_k<false, true, true, false><<<g1, blk, 0, stream>>>(
          Hb, W2T + (size_t)l * 32768, b2_l, X, (float*)d_out, nullptr, N, 256, 128);
    }
  }
}

// Round 5
// 610.420 us; speedup vs baseline: 19.1076x; 1.1353x over previous
//
#include <hip/hip_runtime.h>

// ---------------------------------------------------------------------------
// GraphTransformer R5: R4 + parallel 3-phase CSR offset scan (was 85us
// single-block serial scan at 0.04% occupancy).
// ---------------------------------------------------------------------------

typedef __attribute__((ext_vector_type(8))) short bf16x8;
typedef __attribute__((ext_vector_type(4))) float f32x4;

__device__ __forceinline__ unsigned short f2bf_rne(float f) {
  unsigned int u = __builtin_bit_cast(unsigned int, f);
  u = (u + 0x7fffu + ((u >> 16) & 1u)) >> 16;
  return (unsigned short)u;
}
__device__ __forceinline__ float bflo(unsigned int w) {
  return __builtin_bit_cast(float, w << 16);
}
__device__ __forceinline__ float bfhi(unsigned int w) {
  return __builtin_bit_cast(float, w & 0xffff0000u);
}

// ---------------- MFMA GEMM: Y = op(A[M,K]b16 @ W + bias) (+R) -------------
// Bt is W transposed: Bt[n][k] bf16. BM=BN=128, BK=128 chunks. 4 waves 2x2.
template<bool RELU, bool RES, bool OUTF, bool OUTB>
__global__ __launch_bounds__(256, 2)
void mgemm_k(const unsigned short* __restrict__ A,
             const unsigned short* __restrict__ Bt,
             const float* __restrict__ bias, const float* __restrict__ R,
             float* __restrict__ Yf, unsigned short* __restrict__ Yb,
             int M, int K, int N) {
  __shared__ __align__(16) char smem[65536];   // A tile 32KB | B tile 32KB
  const int t = threadIdx.x;
  const int l = t & 63;
  const int w = t >> 6, wm = w >> 1, wn = w & 1;
  const int row0 = blockIdx.x * 128;
  const int col0 = blockIdx.y * 128;

  f32x4 acc[4][4];
#pragma unroll
  for (int m = 0; m < 4; m++)
#pragma unroll
    for (int n = 0; n < 4; n++)
#pragma unroll
      for (int r = 0; r < 4; r++) acc[m][n][r] = 0.f;

  for (int kc = 0; kc < K; kc += 128) {
    if (kc) __syncthreads();
    // stage A tile: 128 rows x 128 bf16 (256B/row), swizzled
#pragma unroll
    for (int j = 0; j < 8; j++) {
      int id = j * 256 + t;
      int row = id >> 4, c16 = id & 15;
      int gr = row0 + row; if (gr >= M) gr = M - 1;
      uint4 val = *(const uint4*)(A + (size_t)gr * K + kc + c16 * 8);
      *(uint4*)(smem + row * 256 + ((c16 * 16) ^ ((row & 7) << 4))) = val;
    }
    // stage B tile (Bt rows = output cols)
#pragma unroll
    for (int j = 0; j < 8; j++) {
      int id = j * 256 + t;
      int row = id >> 4, c16 = id & 15;
      uint4 val = *(const uint4*)(Bt + (size_t)(col0 + row) * K + kc + c16 * 8);
      *(uint4*)(smem + 32768 + row * 256 + ((c16 * 16) ^ ((row & 7) << 4))) = val;
    }
    __syncthreads();

#pragma unroll
    for (int ks = 0; ks < 4; ks++) {
      const int bofs = ks * 64 + (l >> 4) * 16;
      bf16x8 a[4], b[4];
#pragma unroll
      for (int m = 0; m < 4; m++) {
        int r = wm * 64 + m * 16 + (l & 15);
        a[m] = *(const bf16x8*)(smem + r * 256 + (bofs ^ ((r & 7) << 4)));
      }
#pragma unroll
      for (int n = 0; n < 4; n++) {
        int r = wn * 64 + n * 16 + (l & 15);
        b[n] = *(const bf16x8*)(smem + 32768 + r * 256 + (bofs ^ ((r & 7) << 4)));
      }
#pragma unroll
      for (int m = 0; m < 4; m++)
#pragma unroll
        for (int n = 0; n < 4; n++)
          acc[m][n] = __builtin_amdgcn_mfma_f32_16x16x32_bf16(a[m], b[n], acc[m][n], 0, 0, 0);
    }
  }

  // epilogue: C[row][col], row=(l>>4)*4+reg (M), col=l&15 (N)
  const int rbase = row0 + wm * 64 + ((l >> 4) << 2);
  const int cl = l & 15;
#pragma unroll
  for (int n = 0; n < 4; n++) {
    int col = col0 + wn * 64 + n * 16 + cl;
    float bb = bias[col];
#pragma unroll
    for (int m = 0; m < 4; m++) {
      int rtile = rbase + m * 16;
#pragma unroll
      for (int r = 0; r < 4; r++) {
        int row = rtile + r;
        if (row < M) {
          float o = acc[m][n][r] + bb;
          if (RES) o += R[(size_t)row * N + col];
          if (RELU) o = fmaxf(o, 0.f);
          if (OUTF) Yf[(size_t)row * N + col] = o;
          if (OUTB) Yb[(size_t)row * N + col] = f2bf_rne(o);
        }
      }
    }
  }
}

// ---------------- weight transpose+cast: dst[m][n][k] = src[m][k][n] -------
__global__ __launch_bounds__(256)
void wtc_k(const float* __restrict__ src, unsigned short* __restrict__ dst,
           int K, int N, int cnt, int dstStrideM) {
  int o = blockIdx.x * 256 + threadIdx.x;
  int total = cnt * K * N;
  if (o >= total) return;
  int m = o / (K * N);
  int rem = o - m * K * N;
  int n = rem / K;
  int k = rem - n * K;
  dst[(size_t)m * dstStrideM + (size_t)n * K + k] = f2bf_rne(src[(size_t)m * K * N + (size_t)k * N + n]);
}

// bias concat: bqkv[l][384] = bq[l] | bk[l] | bv[l]
__global__ __launch_bounds__(256)
void bcat_k(const float* __restrict__ bq, const float* __restrict__ bk,
            const float* __restrict__ bv, float* __restrict__ bqkv) {
  int idx = blockIdx.x * 256 + threadIdx.x;
  if (idx >= 768) return;
  int l = idx / 384, c = idx - l * 384;
  float v = (c < 128) ? bq[l * 128 + c] : (c < 256) ? bk[l * 128 + c - 128] : bv[l * 128 + c - 256];
  bqkv[idx] = v;
}

// f32 -> bf16 cast, 8 elems/thread
__global__ __launch_bounds__(256)
void xcast_k(const float* __restrict__ x, unsigned short* __restrict__ xb, int n8) {
  int i = blockIdx.x * 256 + threadIdx.x;
  if (i >= n8) return;
  const float4* p = (const float4*)(x + (size_t)i * 8);
  float4 a = p[0], b = p[1];
  ushort4* q = (ushort4*)(xb + (size_t)i * 8);
  q[0] = make_ushort4(f2bf_rne(a.x), f2bf_rne(a.y), f2bf_rne(a.z), f2bf_rne(a.w));
  q[1] = make_ushort4(f2bf_rne(b.x), f2bf_rne(b.y), f2bf_rne(b.z), f2bf_rne(b.w));
}

// ---------------- edge scores (bf16 QKV, [n][384] layout) ------------------
__global__ __launch_bounds__(256)
void scores_k(const unsigned short* __restrict__ QKV,
              const int* __restrict__ srcP, const int* __restrict__ dstP,
              float* __restrict__ Sp, int E, float scale) {
  int idx = blockIdx.x * 256 + threadIdx.x;
  if (idx >= E * 4) return;
  int i = idx >> 2, h = idx & 3;
  const uint4* qp = (const uint4*)(QKV + (size_t)dstP[i] * 384 + h * 32);
  const uint4* kp = (const uint4*)(QKV + (size_t)srcP[i] * 384 + 128 + h * 32);
  float s = 0.f;
#pragma unroll
  for (int j = 0; j < 4; j++) {
    uint4 q4 = qp[j], k4 = kp[j];
    s += bflo(q4.x) * bflo(k4.x) + bfhi(q4.x) * bfhi(k4.x);
    s += bflo(q4.y) * bflo(k4.y) + bfhi(q4.y) * bfhi(k4.y);
    s += bflo(q4.z) * bflo(k4.z) + bfhi(q4.z) * bfhi(k4.z);
    s += bflo(q4.w) * bflo(k4.w) + bfhi(q4.w) * bfhi(k4.w);
  }
  Sp[idx] = s * scale;
}

// ---------------- softmax reductions (two-stage, per head) -----------------
__global__ __launch_bounds__(256)
void reduce1_max(const float* __restrict__ S, float* __restrict__ pmax, int total) {
  __shared__ float sm[256];
  int t = threadIdx.x;
  int start = blockIdx.x * 256 + t;
  float v = -__builtin_huge_valf();
  for (int i = start; i < total; i += 256 * 256) v = fmaxf(v, S[i]);
  sm[t] = v; __syncthreads();
  for (int s = 128; s >= 4; s >>= 1) {
    if (t < s) sm[t] = fmaxf(sm[t], sm[t + s]);
    __syncthreads();
  }
  if (t < 4) pmax[blockIdx.x * 4 + t] = sm[t];
}

__global__ __launch_bounds__(256)
void reduce2_max(const float* __restrict__ p, float* __restrict__ m) {
  __shared__ float sm[256];
  int t = threadIdx.x;
  float v = p[t];
  v = fmaxf(v, p[t + 256]); v = fmaxf(v, p[t + 512]); v = fmaxf(v, p[t + 768]);
  sm[t] = v; __syncthreads();
  for (int s = 128; s >= 4; s >>= 1) {
    if (t < s) sm[t] = fmaxf(sm[t], sm[t + s]);
    __syncthreads();
  }
  if (t < 4) m[t] = sm[t];
}

__global__ __launch_bounds__(256)
void expsum1(float* __restrict__ S, const float* __restrict__ m,
             float* __restrict__ psum, int total) {
  __shared__ float sm[256];
  int t = threadIdx.x;
  int start = blockIdx.x * 256 + t;
  float mh = m[t & 3];
  float acc = 0.f;
  for (int i = start; i < total; i += 256 * 256) {
    float a = expf(S[i] - mh);
    S[i] = a;
    acc += a;
  }
  sm[t] = acc; __syncthreads();
  for (int s = 128; s >= 4; s >>= 1) {
    if (t < s) sm[t] += sm[t + s];
    __syncthreads();
  }
  if (t < 4) psum[blockIdx.x * 4 + t] = sm[t];
}

__global__ __launch_bounds__(256)
void reduce2_sum(const float* __restrict__ p, float* __restrict__ iz) {
  __shared__ float sm[256];
  int t = threadIdx.x;
  float v = p[t] + p[t + 256] + p[t + 512] + p[t + 768];
  sm[t] = v; __syncthreads();
  for (int s = 128; s >= 4; s >>= 1) {
    if (t < s) sm[t] += sm[t + s];
    __syncthreads();
  }
  if (t < 4) iz[t] = 1.0f / sm[t];
}

// ---------------- CSR build ----------------
__global__ __launch_bounds__(256)
void zeroi_k(int* __restrict__ p, int n) {
  int i = blockIdx.x * 256 + threadIdx.x;
  if (i < n) p[i] = 0;
}

__global__ __launch_bounds__(256)
void hist_k(const int* __restrict__ dst, int* __restrict__ cnt, int E) {
  int i = blockIdx.x * 256 + threadIdx.x;
  if (i < E) atomicAdd(&cnt[dst[i]], 1);
}

// ---- 3-phase exclusive scan over cnt[0..N) -> off[0..N] -------------------
// phase 1: per-block (2048 elems) totals
__global__ __launch_bounds__(256)
void scan1_k(const int* __restrict__ cnt, int* __restrict__ bsum, int N) {
  __shared__ int sm[256];
  int b = blockIdx.x, t = threadIdx.x;
  int base = b * 2048 + t * 8;
  int s = 0;
#pragma unroll
  for (int j = 0; j < 8; j++) {
    int i = base + j;
    if (i < N) s += cnt[i];
  }
  sm[t] = s; __syncthreads();
  for (int d = 128; d >= 1; d >>= 1) {
    if (t < d) sm[t] += sm[t + d];
    __syncthreads();
  }
  if (t == 0) bsum[b] = sm[0];
}

// phase 2: serial exclusive scan of block totals (nb ~ 25) + total -> off[N]
__global__ __launch_bounds__(64)
void scan2_k(int* __restrict__ bsum, int* __restrict__ off, int nb, int N) {
  if (threadIdx.x == 0 && blockIdx.x == 0) {
    int run = 0;
    for (int b = 0; b < nb; b++) { int v = bsum[b]; bsum[b] = run; run += v; }
    off[N] = run;
  }
}

// phase 3: local exclusive scan + block base
__global__ __launch_bounds__(256)
void scan3_k(const int* __restrict__ cnt, const int* __restrict__ bsum,
             int* __restrict__ off, int N) {
  __shared__ int sm[256];
  int b = blockIdx.x, t = threadIdx.x;
  int base = b * 2048 + t * 8;
  int vals[8];
  int s = 0;
#pragma unroll
  for (int j = 0; j < 8; j++) {
    int i = base + j;
    vals[j] = (i < N) ? cnt[i] : 0;
    s += vals[j];
  }
  sm[t] = s; __syncthreads();
  for (int d = 1; d < 256; d <<= 1) {
    int v = (t >= d) ? sm[t - d] : 0;
    __syncthreads();
    sm[t] += v;
    __syncthreads();
  }
  int run = bsum[b] + sm[t] - s;   // exclusive prefix for this thread
#pragma unroll
  for (int j = 0; j < 8; j++) {
    int i = base + j;
    if (i < N) { off[i] = run; run += vals[j]; }
  }
}

__global__ __launch_bounds__(256)
void scatter_k(const int* __restrict__ dst, const int* __restrict__ off,
               int* __restrict__ cur, int* __restrict__ perm, int E) {
  int e = blockIdx.x * 256 + threadIdx.x;
  if (e < E) {
    int d = dst[e];
    int p = atomicAdd(&cur[d], 1);
    perm[off[d] + p] = e;
  }
}

__global__ __launch_bounds__(256)
void sortbuckets_k(const int* __restrict__ off, int* __restrict__ perm, int N) {
  int n = blockIdx.x * 256 + threadIdx.x;
  if (n >= N) return;
  int lo = off[n], hi = off[n + 1];
  for (int i = lo + 1; i < hi; i++) {
    int key = perm[i];
    int j = i - 1;
    while (j >= lo && perm[j] > key) { perm[j + 1] = perm[j]; j--; }
    perm[j + 1] = key;
  }
}

__global__ __launch_bounds__(256)
void meta_k(const int* __restrict__ perm, const int* __restrict__ src,
            const int* __restrict__ dst, int* __restrict__ srcP,
            int* __restrict__ dstP, int E) {
  int i = blockIdx.x * 256 + threadIdx.x;
  if (i < E) {
    int e = perm[i];
    srcP[i] = src[e];
    dstP[i] = dst[e];
  }
}

// ---------------- aggregation gather (bf16 V inside QKV, bf16 out) ---------
__global__ __launch_bounds__(256)
void gatheragg_k(const float* __restrict__ Sp, const float* __restrict__ iz,
                 const unsigned short* __restrict__ QKV,
                 const int* __restrict__ srcP, const int* __restrict__ off,
                 unsigned short* __restrict__ AGb, int N) {
  int node = blockIdx.x * 4 + (threadIdx.x >> 6);
  if (node >= N) return;
  int l = threadIdx.x & 63;        // lane owns cols {2l, 2l+1}
  int h = l >> 4;
  float izh = iz[h];
  int lo = off[node], hi = off[node + 1];
  float ax = 0.f, ay = 0.f;
  int i = lo;
  for (; i + 4 <= hi; i += 4) {
    int s0 = srcP[i], s1 = srcP[i + 1], s2 = srcP[i + 2], s3 = srcP[i + 3];
    float c0 = Sp[i * 4 + h];
    float c1 = Sp[(i + 1) * 4 + h];
    float c2 = Sp[(i + 2) * 4 + h];
    float c3 = Sp[(i + 3) * 4 + h];
    unsigned int v0 = *(const unsigned int*)(QKV + (size_t)s0 * 384 + 256 + l * 2);
    unsigned int v1 = *(const unsigned int*)(QKV + (size_t)s1 * 384 + 256 + l * 2);
    unsigned int v2 = *(const unsigned int*)(QKV + (size_t)s2 * 384 + 256 + l * 2);
    unsigned int v3 = *(const unsigned int*)(QKV + (size_t)s3 * 384 + 256 + l * 2);
    c0 *= izh; c1 *= izh; c2 *= izh; c3 *= izh;
    ax = fmaf(c0, bflo(v0), ax); ay = fmaf(c0, bfhi(v0), ay);
    ax = fmaf(c1, bflo(v1), ax); ay = fmaf(c1, bfhi(v1), ay);
    ax = fmaf(c2, bflo(v2), ax); ay = fmaf(c2, bfhi(v2), ay);
    ax = fmaf(c3, bflo(v3), ax); ay = fmaf(c3, bfhi(v3), ay);
  }
  for (; i < hi; i++) {
    int s = srcP[i];
    float c = Sp[i * 4 + h] * izh;
    unsigned int v = *(const unsigned int*)(QKV + (size_t)s * 384 + 256 + l * 2);
    ax = fmaf(c, bflo(v), ax); ay = fmaf(c, bfhi(v), ay);
  }
  unsigned int packed = (unsigned int)f2bf_rne(ax) | ((unsigned int)f2bf_rne(ay) << 16);
  ((unsigned int*)AGb)[(size_t)node * 64 + l] = packed;
}

// ---------------------------------------------------------------------------
extern "C" void kernel_launch(void* const* d_in, const int* in_sizes, int n_in,
                              void* d_out, int out_size, void* d_ws, size_t ws_size,
                              hipStream_t stream) {
  const float* x_in = (const float*)d_in[0];
  const int*   ei   = (const int*)d_in[1];
  const float* Wi = (const float*)d_in[2];
  const float* bi = (const float*)d_in[3];
  const float* Wq = (const float*)d_in[4];  const float* bq = (const float*)d_in[5];
  const float* Wk = (const float*)d_in[6];  const float* bk = (const float*)d_in[7];
  const float* Wv = (const float*)d_in[8];  const float* bv = (const float*)d_in[9];
  const float* Wo = (const float*)d_in[10]; const float* bo = (const float*)d_in[11];
  const float* W1 = (const float*)d_in[12]; const float* b1 = (const float*)d_in[13];
  const float* W2 = (const float*)d_in[14]; const float* b2 = (const float*)d_in[15];

  const int N = in_sizes[0] / 128;   // 50000
  const int E = in_sizes[1] / 2;     // 800000
  const int* src = ei;
  const int* dst = ei + E;

  char* w = (char*)d_ws;
  auto alloc = [&](size_t bytes) -> char* {
    char* p = w;
    w += (bytes + 255) & ~(size_t)255;
    return p;
  };
  float*          X    = (float*)alloc((size_t)N * 128 * 4);
  unsigned short* Xb   = (unsigned short*)alloc((size_t)N * 128 * 2);
  unsigned short* QKVb = (unsigned short*)alloc((size_t)N * 384 * 2);
  unsigned short* Hb   = QKVb;                 // FFN hidden aliases QKV (dead)
  unsigned short* AGb  = (unsigned short*)alloc((size_t)N * 128 * 2);
  float*          Sp   = (float*)alloc((size_t)E * 4 * 4);
  float* pmax = (float*)alloc(1024 * 4);
  float* psum = (float*)alloc(1024 * 4);
  float* m4   = (float*)alloc(16);
  float* iz   = (float*)alloc(16);
  unsigned short* WiT   = (unsigned short*)alloc(16384 * 2);
  unsigned short* WqkvT = (unsigned short*)alloc((size_t)2 * 384 * 128 * 2);
  unsigned short* WoT   = (unsigned short*)alloc((size_t)2 * 16384 * 2);
  unsigned short* W1T   = (unsigned short*)alloc((size_t)2 * 32768 * 2);
  unsigned short* W2T   = (unsigned short*)alloc((size_t)2 * 32768 * 2);
  float* bqkv = (float*)alloc(768 * 4);
  int* cnt  = (int*)alloc((size_t)N * 4);
  int* off  = (int*)alloc((size_t)(N + 1) * 4);
  int* cur  = (int*)alloc((size_t)N * 4);
  int* perm = (int*)alloc((size_t)E * 4);
  int* srcP = (int*)alloc((size_t)E * 4);
  int* dstP = (int*)alloc((size_t)E * 4);
  int* bsum = (int*)alloc(256 * 4);

  const float scale = 0.17677669529663687f; // 1/sqrt(32)
  dim3 blk(256);
  const int gx = (N + 127) / 128;            // 391
  dim3 g1(gx, 1), g2(gx, 2), g3(gx, 3);
  const int tot = E * 4;
  const int gE = (tot + 255) / 256;
  const int gEe = (E + 255) / 256;
  const int gN = (N + 255) / 256;
  const int gAgg = (N + 3) / 4;
  const int nScanB = (N + 2047) / 2048;      // 25

  // ---- CSR build ----
  zeroi_k<<<gN, blk, 0, stream>>>(cnt, N);
  zeroi_k<<<gN, blk, 0, stream>>>(cur, N);
  hist_k<<<gEe, blk, 0, stream>>>(dst, cnt, E);
  scan1_k<<<nScanB, blk, 0, stream>>>(cnt, bsum, N);
  scan2_k<<<1, 64, 0, stream>>>(bsum, off, nScanB, N);
  scan3_k<<<nScanB, blk, 0, stream>>>(cnt, bsum, off, N);
  scatter_k<<<gEe, blk, 0, stream>>>(dst, off, cur, perm, E);
  sortbuckets_k<<<gN, blk, 0, stream>>>(off, perm, N);
  meta_k<<<gEe, blk, 0, stream>>>(perm, src, dst, srcP, dstP, E);

  // ---- weight prep (transpose + bf16 cast) ----
  wtc_k<<<(16384 + 255) / 256, blk, 0, stream>>>(Wi, WiT, 128, 128, 1, 16384);
  wtc_k<<<(2 * 16384 + 255) / 256, blk, 0, stream>>>(Wq, WqkvT, 128, 128, 2, 384 * 128);
  wtc_k<<<(2 * 16384 + 255) / 256, blk, 0, stream>>>(Wk, WqkvT + 128 * 128, 128, 128, 2, 384 * 128);
  wtc_k<<<(2 * 16384 + 255) / 256, blk, 0, stream>>>(Wv, WqkvT + 256 * 128, 128, 128, 2, 384 * 128);
  wtc_k<<<(2 * 16384 + 255) / 256, blk, 0, stream>>>(Wo, WoT, 128, 128, 2, 16384);
  wtc_k<<<(2 * 32768 + 255) / 256, blk, 0, stream>>>(W1, W1T, 128, 256, 2, 32768);
  wtc_k<<<(2 * 32768 + 255) / 256, blk, 0, stream>>>(W2, W2T, 256, 128, 2, 32768);
  bcat_k<<<3, blk, 0, stream>>>(bq, bk, bv, bqkv);

  // ---- input cast + projection (cast into AGb region, free until agg) ----
  xcast_k<<<(N * 16 + 255) / 256, blk, 0, stream>>>(x_in, AGb, N * 16);
  mgemm_k<false, false, true, true><<<g1, blk, 0, stream>>>(AGb, WiT, bi, nullptr, X, Xb, N, 128, 128);

  for (int l = 0; l < 2; l++) {
    const float* bo_l = bo + l * 128;
    const float* b1_l = b1 + l * 256;
    const float* b2_l = b2 + l * 128;

    // QKV fused: [N][384] bf16
    mgemm_k<false, false, false, true><<<g3, blk, 0, stream>>>(
        Xb, WqkvT + (size_t)l * 384 * 128, bqkv + l * 384, nullptr, nullptr, QKVb, N, 128, 384);

    scores_k<<<gE, blk, 0, stream>>>(QKVb, srcP, dstP, Sp, E, scale);
    reduce1_max<<<256, blk, 0, stream>>>(Sp, pmax, tot);
    reduce2_max<<<1, blk, 0, stream>>>(pmax, m4);
    expsum1<<<256, blk, 0, stream>>>(Sp, m4, psum, tot);
    reduce2_sum<<<1, blk, 0, stream>>>(psum, iz);

    gatheragg_k<<<gAgg, blk, 0, stream>>>(Sp, iz, QKVb, srcP, off, AGb, N);

    // x = x + AG@Wo + bo
    mgemm_k<false, true, true, true><<<g1, blk, 0, stream>>>(
        AGb, WoT + (size_t)l * 16384, bo_l, X, X, Xb, N, 128, 128);
    // h = relu(x@W1 + b1), bf16 only
    mgemm_k<true, false, false, true><<<g2, blk, 0, stream>>>(
        Xb, W1T + (size_t)l * 32768, b1_l, nullptr, nullptr, Hb, N, 128, 256);
    // x = x + h@W2 + b2
    if (l == 0) {
      mgemm_k<false, true, true, true><<<g1, blk, 0, stream>>>(
          Hb, W2T + (size_t)l * 32768, b2_l, X, X, Xb, N, 256, 128);
    } else {
      mgemm_k<false, true, true, false><<<g1, blk, 0, stream>>>(
          Hb, W2T + (size_t)l * 32768, b2_l, X, (float*)d_out, nullptr, N, 256, 128);
    }
  }
}